// Round 1
// baseline (194.387 us; speedup 1.0000x reference)
//
#include <hip/hip_runtime.h>
#include <math.h>

#define T_LEN  65536
#define T_PAD  65792      // T + STEP
#define C_CH   64
#define WS_    512
#define STEP_  256
#define K_     257        // WS/2 + 1

// pad every 16 float2 (128B) to break power-of-2 LDS bank patterns
#define PIDX(i) ((i) + ((i) >> 4))

__device__ __forceinline__ float2 cmul(float2 a, float2 b) {
    return make_float2(a.x * b.x - a.y * b.y, a.x * b.y + a.y * b.x);
}
__device__ __forceinline__ float2 cadd(float2 a, float2 b) { return make_float2(a.x + b.x, a.y + b.y); }
__device__ __forceinline__ float2 csub(float2 a, float2 b) { return make_float2(a.x - b.x, a.y - b.y); }

// One radix-4 Stockham stage of a 256-point FFT. 64 lanes, one butterfly each.
// SGN=+1: forward (e^-), SGN=-1: inverse (e^+), unnormalized.
template <int N_, int S_, int SGN>
__device__ __forceinline__ void fft_stage(int lane,
                                          const float2* __restrict__ x,
                                          float2* __restrict__ y,
                                          const float2* __restrict__ tw) {
    constexpr int M_ = N_ >> 2;
    int p = lane / S_;
    int q = lane - p * S_;
    float2 a = x[PIDX(q + S_ * p)];
    float2 b = x[PIDX(q + S_ * (p + M_))];
    float2 c = x[PIDX(q + S_ * (p + 2 * M_))];
    float2 d = x[PIDX(q + S_ * (p + 3 * M_))];
    float2 w1 = tw[p * (256 / N_)];   // e^{-2pi i p/N}
    if (SGN < 0) w1.y = -w1.y;
    float2 w2 = cmul(w1, w1);
    float2 w3 = cmul(w2, w1);
    float2 apc = cadd(a, c), amc = csub(a, c);
    float2 bpd = cadd(b, d), bmd = csub(b, d);
    float2 jb = make_float2(-bmd.y, bmd.x);   // i*(b-d)
    float2 t1, t3;
    if (SGN > 0) { t1 = csub(amc, jb); t3 = cadd(amc, jb); }
    else         { t1 = cadd(amc, jb); t3 = csub(amc, jb); }
    y[PIDX(q + S_ * (4 * p + 0))] = cadd(apc, bpd);
    y[PIDX(q + S_ * (4 * p + 1))] = cmul(w1, t1);
    y[PIDX(q + S_ * (4 * p + 2))] = cmul(w2, csub(apc, bpd));
    y[PIDX(q + S_ * (4 * p + 3))] = cmul(w3, t3);
}

// ---------------- kernel 1: channel mix + zero pad -------------------------
__global__ __launch_bounds__(512, 1) void mix_kernel(const float* __restrict__ x,
                                                     const float* __restrict__ mixer,
                                                     float* __restrict__ mixed) {
    __shared__ __align__(16) float xt[64][128];
    __shared__ __align__(16) float mx[64][64];
    int tid = threadIdx.x;
    int b   = blockIdx.y;
    int t0  = blockIdx.x * 128;

    if (t0 >= T_LEN) {   // zero-pad region [T, T_PAD)
        for (int f = tid; f < 8192; f += 512) {
            int d = f >> 7, tt = f & 127;
            mixed[((size_t)(b * C_CH + d)) * T_PAD + t0 + tt] = 0.0f;
        }
        return;
    }
    for (int f = tid; f < 4096; f += 512) reinterpret_cast<float*>(mx)[f] = mixer[f];
    // load x tile as float4
    for (int f4 = tid; f4 < 2048; f4 += 512) {
        int cc = f4 >> 5, tt4 = f4 & 31;
        *reinterpret_cast<float4*>(&xt[cc][tt4 * 4]) =
            *reinterpret_cast<const float4*>(&x[((size_t)(b * C_CH + cc)) * T_LEN + t0 + tt4 * 4]);
    }
    __syncthreads();

    int t = tid & 127, w = tid >> 7;
    int dbase = w * 16;
    float acc[16];
#pragma unroll
    for (int i = 0; i < 16; ++i) acc[i] = 0.0f;
    for (int cc = 0; cc < 64; ++cc) {
        float xv = xt[cc][t];
        float4 m0 = *reinterpret_cast<const float4*>(&mx[cc][dbase + 0]);
        float4 m1 = *reinterpret_cast<const float4*>(&mx[cc][dbase + 4]);
        float4 m2 = *reinterpret_cast<const float4*>(&mx[cc][dbase + 8]);
        float4 m3 = *reinterpret_cast<const float4*>(&mx[cc][dbase + 12]);
        acc[0]  = fmaf(xv, m0.x, acc[0]);  acc[1]  = fmaf(xv, m0.y, acc[1]);
        acc[2]  = fmaf(xv, m0.z, acc[2]);  acc[3]  = fmaf(xv, m0.w, acc[3]);
        acc[4]  = fmaf(xv, m1.x, acc[4]);  acc[5]  = fmaf(xv, m1.y, acc[5]);
        acc[6]  = fmaf(xv, m1.z, acc[6]);  acc[7]  = fmaf(xv, m1.w, acc[7]);
        acc[8]  = fmaf(xv, m2.x, acc[8]);  acc[9]  = fmaf(xv, m2.y, acc[9]);
        acc[10] = fmaf(xv, m2.z, acc[10]); acc[11] = fmaf(xv, m2.w, acc[11]);
        acc[12] = fmaf(xv, m3.x, acc[12]); acc[13] = fmaf(xv, m3.y, acc[13]);
        acc[14] = fmaf(xv, m3.z, acc[14]); acc[15] = fmaf(xv, m3.w, acc[15]);
    }
#pragma unroll
    for (int i = 0; i < 16; ++i)
        mixed[((size_t)(b * C_CH + dbase + i)) * T_PAD + t0 + t] = acc[i];
}

// -------- kernel 2: fused STFT -> scan -> iSTFT -> window -> OLA -> tanh ---
// One block per (b,c). 512 threads = 8 waves; wave g handles frame s0+g.
__global__ __launch_bounds__(512, 1) void stft_kernel(const float* __restrict__ mixed,
                                                      const float* __restrict__ transfer,
                                                      const float* __restrict__ gainp,
                                                      float* __restrict__ out) {
    __shared__ float2 buf[8][2][272];          // ping/pong, 256 complex + pad
    __shared__ float2 spec[8][K_];
    __shared__ float2 carry[K_];
    __shared__ float  trrow[K_];
    __shared__ float2 tw256[64];               // e^{-2pi i j/256}, j<64
    __shared__ float2 tw512[K_];               // e^{-i pi k/256}, k<=256
    __shared__ __align__(16) float hannw[512]; // hann(j)/512
    __shared__ __align__(16) float tail[256];

    int tid = threadIdx.x;
    int bc  = blockIdx.x;
    int b   = bc >> 6, c = bc & 63;

    for (int j = tid; j < 64; j += 512) {
        float s, co; sincosf(6.2831853071795864f * (float)j / 256.0f, &s, &co);
        tw256[j] = make_float2(co, -s);
    }
    for (int k = tid; k < K_; k += 512) {
        float s, co; sincosf(3.1415926535897932f * (float)k / 256.0f, &s, &co);
        tw512[k] = make_float2(co, -s);
        trrow[k] = transfer[c * K_ + k];
        carry[k] = make_float2(0.0f, 0.0f);
    }
    for (int j = tid; j < 512; j += 512)
        hannw[j] = (0.5f - 0.5f * cosf(6.2831853071795864f * (float)j / 512.0f)) * (1.0f / 512.0f);
    if (tid < 256) tail[tid] = 0.0f;
    __syncthreads();

    const float* src = mixed + ((size_t)(b * C_CH + c)) * T_PAD;
    float*       dst = out   + ((size_t)(b * C_CH + c)) * T_LEN;
    float gv = gainp[0];

    int g = tid >> 6, lane = tid & 63;
    float2* bin  = buf[g][0];
    float2* btmp = buf[g][1];

    for (int it = 0; it < 32; ++it) {
        int s0 = it * 8;
        // ---- load frame s0+g, packed z[n] = (f[2n], f[2n+1])
        {
            const float* fp = src + (size_t)(s0 + g) * STEP_;
#pragma unroll
            for (int qq = 0; qq < 2; ++qq) {
                int m4 = lane + 64 * qq;                 // float4 index 0..127
                float4 v = *reinterpret_cast<const float4*>(fp + 4 * m4);
                bin[PIDX(2 * m4)]     = make_float2(v.x, v.y);
                bin[PIDX(2 * m4 + 1)] = make_float2(v.z, v.w);
            }
        }
        __syncthreads();
        // ---- forward FFT-256 (4 radix-4 Stockham stages)
        fft_stage<256, 1,  1>(lane, bin,  btmp, tw256); __syncthreads();
        fft_stage<64,  4,  1>(lane, btmp, bin,  tw256); __syncthreads();
        fft_stage<16,  16, 1>(lane, bin,  btmp, tw256); __syncthreads();
        fft_stage<4,   64, 1>(lane, btmp, bin,  tw256); __syncthreads();
        // ---- Hermitian split: rfft-512 spectrum F[0..256]
#pragma unroll
        for (int qq = 0; qq < 5; ++qq) {
            int k = lane + 64 * qq;
            if (k < K_) {
                float2 u = bin[PIDX(k & 255)];
                float2 v = bin[PIDX((256 - k) & 255)];
                float2 E = make_float2(0.5f * (u.x + v.x),  0.5f * (u.y - v.y));
                float2 O = make_float2(0.5f * (u.y + v.y), -0.5f * (u.x - v.x));
                spec[g][k] = cadd(E, cmul(tw512[k], O));
            }
        }
        __syncthreads();
        // ---- IIR scan across the 8 frames (re/im are independent real chains)
        {
            float* sf = reinterpret_cast<float*>(&spec[0][0]);
            float* cf = reinterpret_cast<float*>(&carry[0]);
            for (int e = tid; e < 514; e += 512) {
                float t = trrow[e >> 1];
                float y = cf[e];
#pragma unroll
                for (int gg = 0; gg < 8; ++gg) {
                    float vv = sf[gg * 514 + e];
                    y = (vv + y) * t;
                    sf[gg * 514 + e] = y;
                }
                cf[e] = y;
            }
        }
        __syncthreads();
        // ---- build G[k] = A + iB for packed inverse
#pragma unroll
        for (int qq = 0; qq < 4; ++qq) {
            int k = lane + 64 * qq;       // 0..255
            float2 u  = spec[g][k];
            float2 s2 = spec[g][256 - k];
            float2 A = make_float2(u.x + s2.x, u.y - s2.y);
            float2 D = make_float2(u.x - s2.x, u.y + s2.y);
            float2 wc = tw512[k]; wc.y = -wc.y;          // e^{+i pi k/256}
            float2 Bv = cmul(D, wc);
            bin[PIDX(k)] = make_float2(A.x - Bv.y, A.y + Bv.x);
        }
        __syncthreads();
        // ---- inverse FFT-256 (unnormalized; 1/512 folded into hannw)
        fft_stage<256, 1,  -1>(lane, bin,  btmp, tw256); __syncthreads();
        fft_stage<64,  4,  -1>(lane, btmp, bin,  tw256); __syncthreads();
        fft_stage<16,  16, -1>(lane, bin,  btmp, tw256); __syncthreads();
        fft_stage<4,   64, -1>(lane, btmp, bin,  tw256); __syncthreads();
        // ---- window + overlap-add + tanh + store (float4 per thread)
        {
            int j0 = lane * 4;
            int n0 = lane * 2;
            float2 lo = bin[PIDX(n0)], hi = bin[PIDX(n0 + 1)];
            float4 hw = *reinterpret_cast<const float4*>(&hannw[j0]);
            float4 val = make_float4(lo.x * hw.x, lo.y * hw.y, hi.x * hw.z, hi.y * hw.w);
            float4 prev;
            if (g == 0) {
                prev = *reinterpret_cast<const float4*>(&tail[j0]);
            } else {
                const float2* pb = buf[g - 1][0];
                float2 plo = pb[PIDX(128 + n0)], phi = pb[PIDX(128 + n0 + 1)];
                float4 pw = *reinterpret_cast<const float4*>(&hannw[256 + j0]);
                prev = make_float4(plo.x * pw.x, plo.y * pw.y, phi.x * pw.z, phi.y * pw.w);
            }
            float4 o;
            o.x = tanhf((val.x + prev.x) * gv);
            o.y = tanhf((val.y + prev.y) * gv);
            o.z = tanhf((val.z + prev.z) * gv);
            o.w = tanhf((val.w + prev.w) * gv);
            *reinterpret_cast<float4*>(dst + (size_t)(s0 + g) * STEP_ + j0) = o;
        }
        __syncthreads();
        // ---- save frame-7 windowed second half as next tail
        if (tid < 256) {
            int m = 256 + tid;
            const float* bf7 = reinterpret_cast<const float*>(&buf[7][0][0]);
            tail[tid] = bf7[2 * PIDX(m >> 1) + (m & 1)] * hannw[m];
        }
        __syncthreads();
    }
}

extern "C" void kernel_launch(void* const* d_in, const int* in_sizes, int n_in,
                              void* d_out, int out_size, void* d_ws, size_t ws_size,
                              hipStream_t stream) {
    (void)in_sizes; (void)n_in; (void)out_size; (void)ws_size;
    const float* x        = (const float*)d_in[0];
    const float* mixer    = (const float*)d_in[1];
    const float* transfer = (const float*)d_in[2];
    const float* gain     = (const float*)d_in[3];
    float* out   = (float*)d_out;
    float* mixed = (float*)d_ws;   // (B, C, T_PAD) f32 = 67.4 MB

    dim3 gmix(T_PAD / 128, 4);
    mix_kernel<<<gmix, 512, 0, stream>>>(x, mixer, mixed);
    stft_kernel<<<256, 512, 0, stream>>>(mixed, transfer, gain, out);
}

// Round 2
// 145.442 us; speedup vs baseline: 1.3365x; 1.3365x over previous
//
#include <hip/hip_runtime.h>
#include <math.h>

#define T_LEN  65536
#define T_PAD  65792      // T + STEP
#define C_CH   64
#define WS_    512
#define STEP_  256
#define K_     257        // WS/2 + 1
#define NW     16         // waves per block
#define NIT    16         // iterations (NW frames each)

// pad every 4 float2 (32B) to break power-of-2 LDS bank patterns
#define PIDX(i) ((i) + ((i) >> 2))

// wave-internal LDS sync: LDS ops of one wave complete in order; this just
// drains lgkm and stops the compiler from reordering LDS accesses across it.
#define WSYNC() asm volatile("s_waitcnt lgkmcnt(0)" ::: "memory")

__device__ __forceinline__ float2 cmul(float2 a, float2 b) {
    return make_float2(a.x * b.x - a.y * b.y, a.x * b.y + a.y * b.x);
}
__device__ __forceinline__ float2 cadd(float2 a, float2 b) { return make_float2(a.x + b.x, a.y + b.y); }
__device__ __forceinline__ float2 csub(float2 a, float2 b) { return make_float2(a.x - b.x, a.y - b.y); }

// One radix-4 Stockham stage of a 256-point FFT. 64 lanes, one butterfly each.
// SGN=+1: forward (e^-), SGN=-1: inverse (e^+), unnormalized.
template <int N_, int S_, int SGN>
__device__ __forceinline__ void fft_stage(int lane,
                                          const float2* __restrict__ x,
                                          float2* __restrict__ y,
                                          const float2* __restrict__ tw) {
    constexpr int M_ = N_ >> 2;
    int p = lane / S_;
    int q = lane - p * S_;
    float2 a = x[PIDX(q + S_ * p)];
    float2 b = x[PIDX(q + S_ * (p + M_))];
    float2 c = x[PIDX(q + S_ * (p + 2 * M_))];
    float2 d = x[PIDX(q + S_ * (p + 3 * M_))];
    float2 w1 = tw[p * (256 / N_)];   // e^{-2pi i p/N}
    if (SGN < 0) w1.y = -w1.y;
    float2 w2 = cmul(w1, w1);
    float2 w3 = cmul(w2, w1);
    float2 apc = cadd(a, c), amc = csub(a, c);
    float2 bpd = cadd(b, d), bmd = csub(b, d);
    float2 jb = make_float2(-bmd.y, bmd.x);   // i*(b-d)
    float2 t1, t3;
    if (SGN > 0) { t1 = csub(amc, jb); t3 = cadd(amc, jb); }
    else         { t1 = cadd(amc, jb); t3 = csub(amc, jb); }
    y[PIDX(q + S_ * (4 * p + 0))] = cadd(apc, bpd);
    y[PIDX(q + S_ * (4 * p + 1))] = cmul(w1, t1);
    y[PIDX(q + S_ * (4 * p + 2))] = cmul(w2, csub(apc, bpd));
    y[PIDX(q + S_ * (4 * p + 3))] = cmul(w3, t3);
}

// ---------------- kernel 1: channel mix + zero pad -------------------------
__global__ __launch_bounds__(512, 1) void mix_kernel(const float* __restrict__ x,
                                                     const float* __restrict__ mixer,
                                                     float* __restrict__ mixed) {
    __shared__ __align__(16) float xt[64][128];
    __shared__ __align__(16) float mx[64][64];
    int tid = threadIdx.x;
    int b   = blockIdx.y;
    int t0  = blockIdx.x * 128;

    if (t0 >= T_LEN) {   // zero-pad region [T, T_PAD)
        for (int f = tid; f < 8192; f += 512) {
            int d = f >> 7, tt = f & 127;
            mixed[((size_t)(b * C_CH + d)) * T_PAD + t0 + tt] = 0.0f;
        }
        return;
    }
    for (int f = tid; f < 4096; f += 512) reinterpret_cast<float*>(mx)[f] = mixer[f];
    for (int f4 = tid; f4 < 2048; f4 += 512) {
        int cc = f4 >> 5, tt4 = f4 & 31;
        *reinterpret_cast<float4*>(&xt[cc][tt4 * 4]) =
            *reinterpret_cast<const float4*>(&x[((size_t)(b * C_CH + cc)) * T_LEN + t0 + tt4 * 4]);
    }
    __syncthreads();

    int t = tid & 127, w = tid >> 7;
    int dbase = w * 16;
    float acc[16];
#pragma unroll
    for (int i = 0; i < 16; ++i) acc[i] = 0.0f;
    for (int cc = 0; cc < 64; ++cc) {
        float xv = xt[cc][t];
        float4 m0 = *reinterpret_cast<const float4*>(&mx[cc][dbase + 0]);
        float4 m1 = *reinterpret_cast<const float4*>(&mx[cc][dbase + 4]);
        float4 m2 = *reinterpret_cast<const float4*>(&mx[cc][dbase + 8]);
        float4 m3 = *reinterpret_cast<const float4*>(&mx[cc][dbase + 12]);
        acc[0]  = fmaf(xv, m0.x, acc[0]);  acc[1]  = fmaf(xv, m0.y, acc[1]);
        acc[2]  = fmaf(xv, m0.z, acc[2]);  acc[3]  = fmaf(xv, m0.w, acc[3]);
        acc[4]  = fmaf(xv, m1.x, acc[4]);  acc[5]  = fmaf(xv, m1.y, acc[5]);
        acc[6]  = fmaf(xv, m1.z, acc[6]);  acc[7]  = fmaf(xv, m1.w, acc[7]);
        acc[8]  = fmaf(xv, m2.x, acc[8]);  acc[9]  = fmaf(xv, m2.y, acc[9]);
        acc[10] = fmaf(xv, m2.z, acc[10]); acc[11] = fmaf(xv, m2.w, acc[11]);
        acc[12] = fmaf(xv, m3.x, acc[12]); acc[13] = fmaf(xv, m3.y, acc[13]);
        acc[14] = fmaf(xv, m3.z, acc[14]); acc[15] = fmaf(xv, m3.w, acc[15]);
    }
#pragma unroll
    for (int i = 0; i < 16; ++i)
        mixed[((size_t)(b * C_CH + dbase + i)) * T_PAD + t0 + t] = acc[i];
}

// -------- kernel 2: fused STFT -> scan -> iSTFT -> window -> OLA -> tanh ---
// One block per (b,c). 1024 threads = 16 waves; wave g handles frame s0+g.
__global__ __launch_bounds__(1024, 1) void stft_kernel(const float* __restrict__ mixed,
                                                       const float* __restrict__ transfer,
                                                       const float* __restrict__ gainp,
                                                       float* __restrict__ out) {
    __shared__ float2 buf[NW][2][320];         // ping/pong, 256 complex + pad
    __shared__ float2 spec[NW][K_];
    __shared__ float2 carry[K_];
    __shared__ float  trrow[K_];
    __shared__ float2 tw256[64];               // e^{-2pi i j/256}, j<64
    __shared__ float2 tw512[K_];               // e^{-i pi k/256}, k<=256
    __shared__ __align__(16) float hannw[512]; // hann(j)/512
    __shared__ __align__(16) float tail[2][256];

    int tid = threadIdx.x;
    int bc  = blockIdx.x;
    int b   = bc >> 6, c = bc & 63;

    int g = tid >> 6, lane = tid & 63;
    const float* src = mixed + ((size_t)(b * C_CH + c)) * T_PAD;
    float*       dst = out   + ((size_t)(b * C_CH + c)) * T_LEN;

    // prefetch iteration 0's frame (frame index = g) into registers
    float4 pf0, pf1;
    {
        const float* fp = src + (size_t)g * STEP_;
        pf0 = *reinterpret_cast<const float4*>(fp + 4 * lane);
        pf1 = *reinterpret_cast<const float4*>(fp + 4 * (lane + 64));
    }

    for (int j = tid; j < 64; j += 1024) {
        float s, co; sincosf(6.2831853071795864f * (float)j / 256.0f, &s, &co);
        tw256[j] = make_float2(co, -s);
    }
    for (int k = tid; k < K_; k += 1024) {
        float s, co; sincosf(3.1415926535897932f * (float)k / 256.0f, &s, &co);
        tw512[k] = make_float2(co, -s);
        trrow[k] = transfer[c * K_ + k];
        carry[k] = make_float2(0.0f, 0.0f);
    }
    if (tid < 512)
        hannw[tid] = (0.5f - 0.5f * cosf(6.2831853071795864f * (float)tid / 512.0f)) * (1.0f / 512.0f);
    if (tid < 512) tail[tid >> 8][tid & 255] = 0.0f;
    __syncthreads();

    float gv = gainp[0];
    float2* bin  = buf[g][0];
    float2* btmp = buf[g][1];

    for (int it = 0; it < NIT; ++it) {
        int s0 = it * NW;
        // ---- store prefetched frame, packed z[n] = (f[2n], f[2n+1])
        bin[PIDX(2 * lane)]            = make_float2(pf0.x, pf0.y);
        bin[PIDX(2 * lane + 1)]        = make_float2(pf0.z, pf0.w);
        bin[PIDX(2 * (lane + 64))]     = make_float2(pf1.x, pf1.y);
        bin[PIDX(2 * (lane + 64) + 1)] = make_float2(pf1.z, pf1.w);
        // ---- issue next iteration's loads (hidden under the FFT work)
        if (it + 1 < NIT) {
            const float* fp = src + (size_t)((it + 1) * NW + g) * STEP_;
            pf0 = *reinterpret_cast<const float4*>(fp + 4 * lane);
            pf1 = *reinterpret_cast<const float4*>(fp + 4 * (lane + 64));
        }
        WSYNC();
        // ---- forward FFT-256 (wave-local, no block barriers)
        fft_stage<256, 1,  1>(lane, bin,  btmp, tw256); WSYNC();
        fft_stage<64,  4,  1>(lane, btmp, bin,  tw256); WSYNC();
        fft_stage<16,  16, 1>(lane, bin,  btmp, tw256); WSYNC();
        fft_stage<4,   64, 1>(lane, btmp, bin,  tw256); WSYNC();
        // ---- Hermitian split: rfft-512 spectrum F[0..256] into spec[g]
#pragma unroll
        for (int qq = 0; qq < 5; ++qq) {
            int k = lane + 64 * qq;
            if (k < K_) {
                float2 u = bin[PIDX(k & 255)];
                float2 v = bin[PIDX((256 - k) & 255)];
                float2 E = make_float2(0.5f * (u.x + v.x),  0.5f * (u.y - v.y));
                float2 O = make_float2(0.5f * (u.y + v.y), -0.5f * (u.x - v.x));
                spec[g][k] = cadd(E, cmul(tw512[k], O));
            }
        }
        __syncthreads();   // B1: all spectra visible
        // ---- IIR scan across the NW frames (re/im independent real chains)
        if (tid < 514) {
            float* sf = reinterpret_cast<float*>(&spec[0][0]);
            float* cf = reinterpret_cast<float*>(&carry[0]);
            int e = tid;
            float t = trrow[e >> 1];
            float y = cf[e];
#pragma unroll
            for (int gg = 0; gg < NW; ++gg) {
                float vv = sf[gg * 514 + e];
                y = (vv + y) * t;
                sf[gg * 514 + e] = y;
            }
            cf[e] = y;
        }
        __syncthreads();   // B2: scanned spectra visible
        // ---- build G[k] = A + iB for packed inverse
#pragma unroll
        for (int qq = 0; qq < 4; ++qq) {
            int k = lane + 64 * qq;       // 0..255
            float2 u  = spec[g][k];
            float2 s2 = spec[g][256 - k];
            float2 A = make_float2(u.x + s2.x, u.y - s2.y);
            float2 D = make_float2(u.x - s2.x, u.y + s2.y);
            float2 wc = tw512[k]; wc.y = -wc.y;          // e^{+i pi k/256}
            float2 Bv = cmul(D, wc);
            bin[PIDX(k)] = make_float2(A.x - Bv.y, A.y + Bv.x);
        }
        WSYNC();
        // ---- inverse FFT-256 (wave-local; 1/512 folded into hannw)
        fft_stage<256, 1,  -1>(lane, bin,  btmp, tw256); WSYNC();
        fft_stage<64,  4,  -1>(lane, btmp, bin,  tw256); WSYNC();
        fft_stage<16,  16, -1>(lane, bin,  btmp, tw256); WSYNC();
        fft_stage<4,   64, -1>(lane, btmp, bin,  tw256);
        __syncthreads();   // B3: all waves' inverse FFTs done
        // ---- window + overlap-add + tanh + store (float4 per thread)
        {
            int pp = it & 1;
            int j0 = lane * 4;
            int n0 = lane * 2;
            float2 lo = bin[PIDX(n0)], hi = bin[PIDX(n0 + 1)];
            float4 hw = *reinterpret_cast<const float4*>(&hannw[j0]);
            float4 val = make_float4(lo.x * hw.x, lo.y * hw.y, hi.x * hw.z, hi.y * hw.w);
            float4 prev;
            if (g == 0) {
                prev = *reinterpret_cast<const float4*>(&tail[pp][j0]);
            } else {
                const float2* pb = buf[g - 1][0];
                float2 plo = pb[PIDX(128 + n0)], phi = pb[PIDX(128 + n0 + 1)];
                float4 pw = *reinterpret_cast<const float4*>(&hannw[256 + j0]);
                prev = make_float4(plo.x * pw.x, plo.y * pw.y, phi.x * pw.z, phi.y * pw.w);
            }
            float4 o;
            o.x = tanhf((val.x + prev.x) * gv);
            o.y = tanhf((val.y + prev.y) * gv);
            o.z = tanhf((val.z + prev.z) * gv);
            o.w = tanhf((val.w + prev.w) * gv);
            *reinterpret_cast<float4*>(dst + (size_t)(s0 + g) * STEP_ + j0) = o;
            // wave NW-1 saves its windowed second half as next iteration's tail
            if (g == NW - 1) {
                float2 tlo = bin[PIDX(128 + n0)], thi = bin[PIDX(128 + n0 + 1)];
                float4 tw4 = *reinterpret_cast<const float4*>(&hannw[256 + j0]);
                float* tl = &tail[pp ^ 1][j0];
                tl[0] = tlo.x * tw4.x; tl[1] = tlo.y * tw4.y;
                tl[2] = thi.x * tw4.z; tl[3] = thi.y * tw4.w;
            }
        }
        __syncthreads();   // B4: buffers free for next iteration
    }
}

extern "C" void kernel_launch(void* const* d_in, const int* in_sizes, int n_in,
                              void* d_out, int out_size, void* d_ws, size_t ws_size,
                              hipStream_t stream) {
    (void)in_sizes; (void)n_in; (void)out_size; (void)ws_size;
    const float* x        = (const float*)d_in[0];
    const float* mixer    = (const float*)d_in[1];
    const float* transfer = (const float*)d_in[2];
    const float* gain     = (const float*)d_in[3];
    float* out   = (float*)d_out;
    float* mixed = (float*)d_ws;   // (B, C, T_PAD) f32 = 67.4 MB

    dim3 gmix(T_PAD / 128, 4);
    mix_kernel<<<gmix, 512, 0, stream>>>(x, mixer, mixed);
    stft_kernel<<<256, 1024, 0, stream>>>(mixed, transfer, gain, out);
}

// Round 3
// 124.268 us; speedup vs baseline: 1.5643x; 1.1704x over previous
//
#include <hip/hip_runtime.h>
#include <math.h>

#define T_LEN  65536
#define T_PAD  65792      // T + STEP
#define C_CH   64
#define STEP_  256
#define K_     257        // WS/2 + 1
#define NW     16         // waves per block
#define NIT    16         // iterations (NW frames each)
#define SPEC_ROW  257
#define SPEC_ROWF (2 * SPEC_ROW)

// pad every 8 float2 (64B) by 2 float2: keeps aligned 4-runs contiguous+16B-aligned
#define PIDX8(i) ((i) + (((i) >> 3) << 1))

#define WSYNC()  asm volatile("s_waitcnt lgkmcnt(0)" ::: "memory")
#define CFENCE() asm volatile("" ::: "memory")

__device__ __forceinline__ float2 cadd(float2 a, float2 b) { return make_float2(a.x + b.x, a.y + b.y); }
__device__ __forceinline__ float2 csub(float2 a, float2 b) { return make_float2(a.x - b.x, a.y - b.y); }
__device__ __forceinline__ float2 cmul(float2 a, float2 b) {
    return make_float2(a.x * b.x - a.y * b.y, a.x * b.y + a.y * b.x);
}
// SGN>0: w*t ; SGN<0: conj(w)*t
template <int SGN>
__device__ __forceinline__ float2 cmulsg(float2 w, float2 t) {
    if (SGN > 0) return make_float2(w.x * t.x - w.y * t.y, w.x * t.y + w.y * t.x);
    else         return make_float2(w.x * t.x + w.y * t.y, w.x * t.y - w.y * t.x);
}

// radix-4 butterfly with twiddles (matches validated fft_stage math)
template <int SGN>
__device__ __forceinline__ void bfly4(float2 z0, float2 z1, float2 z2, float2 z3,
                                      float2& o0, float2& o1, float2& o2, float2& o3,
                                      float2 w1, float2 w2, float2 w3) {
    float2 apc = cadd(z0, z2), amc = csub(z0, z2);
    float2 bpd = cadd(z1, z3), bmd = csub(z1, z3);
    float2 jb  = make_float2(-bmd.y, bmd.x);
    float2 t1, t3;
    if (SGN > 0) { t1 = csub(amc, jb); t3 = cadd(amc, jb); }
    else         { t1 = cadd(amc, jb); t3 = csub(amc, jb); }
    o0 = cadd(apc, bpd);
    o1 = cmulsg<SGN>(w1, t1);
    o2 = cmulsg<SGN>(w2, csub(apc, bpd));
    o3 = cmulsg<SGN>(w3, t3);
}
// twiddle-free variant (stage 4: p=0 -> w=1)
template <int SGN>
__device__ __forceinline__ void bfly4nt(float2 z0, float2 z1, float2 z2, float2 z3,
                                        float2& o0, float2& o1, float2& o2, float2& o3) {
    float2 apc = cadd(z0, z2), amc = csub(z0, z2);
    float2 bpd = cadd(z1, z3), bmd = csub(z1, z3);
    float2 jb  = make_float2(-bmd.y, bmd.x);
    o0 = cadd(apc, bpd);
    o2 = csub(apc, bpd);
    if (SGN > 0) { o1 = csub(amc, jb); o3 = cadd(amc, jb); }
    else         { o1 = cadd(amc, jb); o3 = csub(amc, jb); }
}

__device__ __forceinline__ float ftanh(float x) {
    float e = __expf(2.0f * x);                      // v_exp_f32
    return 1.0f - 2.0f * __builtin_amdgcn_rcpf(e + 1.0f);
}

// ---------------- kernel 1: channel mix + zero pad (unchanged) -------------
__global__ __launch_bounds__(512, 1) void mix_kernel(const float* __restrict__ x,
                                                     const float* __restrict__ mixer,
                                                     float* __restrict__ mixed) {
    __shared__ __align__(16) float xt[64][128];
    __shared__ __align__(16) float mx[64][64];
    int tid = threadIdx.x;
    int b   = blockIdx.y;
    int t0  = blockIdx.x * 128;

    if (t0 >= T_LEN) {
        for (int f = tid; f < 8192; f += 512) {
            int d = f >> 7, tt = f & 127;
            mixed[((size_t)(b * C_CH + d)) * T_PAD + t0 + tt] = 0.0f;
        }
        return;
    }
    for (int f = tid; f < 4096; f += 512) reinterpret_cast<float*>(mx)[f] = mixer[f];
    for (int f4 = tid; f4 < 2048; f4 += 512) {
        int cc = f4 >> 5, tt4 = f4 & 31;
        *reinterpret_cast<float4*>(&xt[cc][tt4 * 4]) =
            *reinterpret_cast<const float4*>(&x[((size_t)(b * C_CH + cc)) * T_LEN + t0 + tt4 * 4]);
    }
    __syncthreads();

    int t = tid & 127, w = tid >> 7;
    int dbase = w * 16;
    float acc[16];
#pragma unroll
    for (int i = 0; i < 16; ++i) acc[i] = 0.0f;
    for (int cc = 0; cc < 64; ++cc) {
        float xv = xt[cc][t];
        float4 m0 = *reinterpret_cast<const float4*>(&mx[cc][dbase + 0]);
        float4 m1 = *reinterpret_cast<const float4*>(&mx[cc][dbase + 4]);
        float4 m2 = *reinterpret_cast<const float4*>(&mx[cc][dbase + 8]);
        float4 m3 = *reinterpret_cast<const float4*>(&mx[cc][dbase + 12]);
        acc[0]  = fmaf(xv, m0.x, acc[0]);  acc[1]  = fmaf(xv, m0.y, acc[1]);
        acc[2]  = fmaf(xv, m0.z, acc[2]);  acc[3]  = fmaf(xv, m0.w, acc[3]);
        acc[4]  = fmaf(xv, m1.x, acc[4]);  acc[5]  = fmaf(xv, m1.y, acc[5]);
        acc[6]  = fmaf(xv, m1.z, acc[6]);  acc[7]  = fmaf(xv, m1.w, acc[7]);
        acc[8]  = fmaf(xv, m2.x, acc[8]);  acc[9]  = fmaf(xv, m2.y, acc[9]);
        acc[10] = fmaf(xv, m2.z, acc[10]); acc[11] = fmaf(xv, m2.w, acc[11]);
        acc[12] = fmaf(xv, m3.x, acc[12]); acc[13] = fmaf(xv, m3.y, acc[13]);
        acc[14] = fmaf(xv, m3.z, acc[14]); acc[15] = fmaf(xv, m3.w, acc[15]);
    }
#pragma unroll
    for (int i = 0; i < 16; ++i)
        mixed[((size_t)(b * C_CH + dbase + i)) * T_PAD + t0 + t] = acc[i];
}

// -------- kernel 2: fused STFT -> scan -> iSTFT -> window -> OLA -> tanh ---
// One block per (b,c). 1024 threads = 16 waves; wave g handles frame it*16+g.
// In-place per-wave FFT (every stage reads {lane+64m}); twiddles/hann in regs.
__global__ __launch_bounds__(1024) void stft_kernel(const float* __restrict__ mixed,
                                                    const float* __restrict__ transfer,
                                                    const float* __restrict__ gainp,
                                                    float* __restrict__ out) {
    __shared__ __align__(16) float2 buf[NW][320];        // per-wave FFT scratch
    __shared__ __align__(16) float2 spec[NW][SPEC_ROW];  // X / Y spectra
    __shared__ __align__(16) float  olab[NW][264];       // OLA neighbor exchange
    __shared__ __align__(16) float  tails[2][264];       // iter-crossing tail

    const int tid  = threadIdx.x;
    const int bc   = blockIdx.x;
    const int b    = bc >> 6, c = bc & 63;
    const int g    = tid >> 6, lane = tid & 63;

    const float* src = mixed + ((size_t)(b * C_CH + c)) * T_PAD;
    float*       dst = out   + ((size_t)(b * C_CH + c)) * T_LEN;

    // ---- prefetch iteration 0's frame (FFT register layout: z[lane+64m])
    float2 pf0, pf1, pf2, pf3;
    {
        const float* fp = src + (size_t)g * STEP_;
        pf0 = *reinterpret_cast<const float2*>(fp + 2 * lane);
        pf1 = *reinterpret_cast<const float2*>(fp + 2 * (lane + 64));
        pf2 = *reinterpret_cast<const float2*>(fp + 2 * (lane + 128));
        pf3 = *reinterpret_cast<const float2*>(fp + 2 * (lane + 192));
    }

    // ---- per-lane constant twiddles (registers)
    const float TWO_PI = 6.2831853071795864f;
    float sn, cn;
    sincosf(TWO_PI * (float)lane / 256.0f, &sn, &cn);
    float2 w1a = make_float2(cn, -sn), w2a = cmul(w1a, w1a), w3a = cmul(w2a, w1a);
    sincosf(TWO_PI * (float)(lane >> 2) / 64.0f, &sn, &cn);
    float2 w1b = make_float2(cn, -sn), w2b = cmul(w1b, w1b), w3b = cmul(w2b, w1b);
    sincosf(TWO_PI * (float)(lane >> 4) / 16.0f, &sn, &cn);
    float2 w1c = make_float2(cn, -sn), w2c = cmul(w1c, w1c), w3c = cmul(w2c, w1c);
    float2 wh[4];
#pragma unroll
    for (int qq = 0; qq < 4; ++qq) {
        sincosf(3.14159265358979f * (float)(lane + 64 * qq) / 256.0f, &sn, &cn);
        wh[qq] = make_float2(cn, -sn);
    }
    // ---- per-lane hann/512 weights (registers)
#define HV(m) ((0.5f - 0.5f * cosf(TWO_PI * (float)(m) / 512.0f)) * (1.0f / 512.0f))
    float h0 = HV(2 * lane),       h1 = HV(2 * lane + 1);
    float h2 = HV(2 * lane + 128), h3 = HV(2 * lane + 129);
    float h4 = HV(2 * lane + 256), h5 = HV(2 * lane + 257);
    float h6 = HV(2 * lane + 384), h7 = HV(2 * lane + 385);
#undef HV

    // ---- scan assignment: 32 lanes per wave; wave 0 lanes 32/33 take 512/513
    int se;
    if (lane < 32) se = (g << 5) | lane;
    else if (g == 0 && lane < 34) se = 480 + lane;
    else se = -1;
    float tcar = 0.0f, ycar = 0.0f;
    if (se >= 0) tcar = transfer[c * K_ + (se >> 1)];

    if (tid < 256) tails[0][tid] = 0.0f;
    const float gv = gainp[0];
    float2* bin = &buf[g][0];
    const int q2 = (lane & 3)  + ((lane >> 2) << 4);   // stage-2 write base
    const int q3 = (lane & 15) + ((lane >> 4) << 6);   // stage-3 write base
    __syncthreads();

    for (int it = 0; it < NIT; ++it) {
        const int f = it * NW + g;
        float2 z0 = pf0, z1 = pf1, z2 = pf2, z3 = pf3;
        if (it + 1 < NIT) {   // prefetch next frame under this iteration's work
            const float* fp = src + (size_t)(f + NW) * STEP_;
            pf0 = *reinterpret_cast<const float2*>(fp + 2 * lane);
            pf1 = *reinterpret_cast<const float2*>(fp + 2 * (lane + 64));
            pf2 = *reinterpret_cast<const float2*>(fp + 2 * (lane + 128));
            pf3 = *reinterpret_cast<const float2*>(fp + 2 * (lane + 192));
        }
        float2 o0, o1, o2, o3;
        // ---- fwd stage 1 (registers) -> LDS
        bfly4<1>(z0, z1, z2, z3, o0, o1, o2, o3, w1a, w2a, w3a);
        {
            float2* bw = bin + PIDX8(4 * lane);
            *reinterpret_cast<float4*>(bw)     = make_float4(o0.x, o0.y, o1.x, o1.y);
            *reinterpret_cast<float4*>(bw + 2) = make_float4(o2.x, o2.y, o3.x, o3.y);
        }
        WSYNC();
        // ---- fwd stage 2 (in-place)
        z0 = bin[PIDX8(lane)]; z1 = bin[PIDX8(lane + 64)];
        z2 = bin[PIDX8(lane + 128)]; z3 = bin[PIDX8(lane + 192)];
        bfly4<1>(z0, z1, z2, z3, o0, o1, o2, o3, w1b, w2b, w3b);
        CFENCE();
        bin[PIDX8(q2)] = o0; bin[PIDX8(q2 + 4)] = o1;
        bin[PIDX8(q2 + 8)] = o2; bin[PIDX8(q2 + 12)] = o3;
        WSYNC();
        // ---- fwd stage 3
        z0 = bin[PIDX8(lane)]; z1 = bin[PIDX8(lane + 64)];
        z2 = bin[PIDX8(lane + 128)]; z3 = bin[PIDX8(lane + 192)];
        bfly4<1>(z0, z1, z2, z3, o0, o1, o2, o3, w1c, w2c, w3c);
        CFENCE();
        bin[PIDX8(q3)] = o0; bin[PIDX8(q3 + 16)] = o1;
        bin[PIDX8(q3 + 32)] = o2; bin[PIDX8(q3 + 48)] = o3;
        WSYNC();
        // ---- fwd stage 4 (no twiddle, in-place same addresses)
        z0 = bin[PIDX8(lane)]; z1 = bin[PIDX8(lane + 64)];
        z2 = bin[PIDX8(lane + 128)]; z3 = bin[PIDX8(lane + 192)];
        bfly4nt<1>(z0, z1, z2, z3, o0, o1, o2, o3);
        CFENCE();
        bin[PIDX8(lane)] = o0; bin[PIDX8(lane + 64)] = o1;
        bin[PIDX8(lane + 128)] = o2; bin[PIDX8(lane + 192)] = o3;
        WSYNC();
        // ---- Hermitian split -> spec[g][0..256]
#pragma unroll
        for (int qq = 0; qq < 4; ++qq) {
            int k = lane + 64 * qq;
            float2 u = bin[PIDX8(k)];
            float2 v = bin[PIDX8((256 - k) & 255)];
            float2 E = make_float2(0.5f * (u.x + v.x),  0.5f * (u.y - v.y));
            float2 O = make_float2(0.5f * (u.y + v.y), -0.5f * (u.x - v.x));
            spec[g][k] = cadd(E, cmul(wh[qq], O));
        }
        if (lane == 0) {
            float2 u0 = bin[PIDX8(0)];
            spec[g][256] = make_float2(u0.x - u0.y, 0.0f);
        }
        __syncthreads();   // B1: all spectra visible
        // ---- IIR scan across the NW frames (carry in registers)
        if (se >= 0) {
            float* sf = reinterpret_cast<float*>(&spec[0][0]);
            float y = ycar;
#pragma unroll
            for (int gg = 0; gg < NW; ++gg) {
                float vv = sf[gg * SPEC_ROWF + se];
                y = (vv + y) * tcar;
                sf[gg * SPEC_ROWF + se] = y;
            }
            ycar = y;
        }
        __syncthreads();   // B2: scanned spectra visible
        // ---- G-build straight into inverse stage-1 registers
        {
            float2 zz[4];
#pragma unroll
            for (int qq = 0; qq < 4; ++qq) {
                int k = lane + 64 * qq;
                float2 u  = spec[g][k];
                float2 s2 = spec[g][256 - k];
                float2 A  = make_float2(u.x + s2.x, u.y - s2.y);
                float2 D  = make_float2(u.x - s2.x, u.y + s2.y);
                float2 Bv = cmulsg<-1>(wh[qq], D);    // D * conj(tw512[k])
                zz[qq] = make_float2(A.x - Bv.y, A.y + Bv.x);
            }
            bfly4<-1>(zz[0], zz[1], zz[2], zz[3], o0, o1, o2, o3, w1a, w2a, w3a);
        }
        {
            float2* bw = bin + PIDX8(4 * lane);
            *reinterpret_cast<float4*>(bw)     = make_float4(o0.x, o0.y, o1.x, o1.y);
            *reinterpret_cast<float4*>(bw + 2) = make_float4(o2.x, o2.y, o3.x, o3.y);
        }
        WSYNC();
        // ---- inv stage 2
        z0 = bin[PIDX8(lane)]; z1 = bin[PIDX8(lane + 64)];
        z2 = bin[PIDX8(lane + 128)]; z3 = bin[PIDX8(lane + 192)];
        bfly4<-1>(z0, z1, z2, z3, o0, o1, o2, o3, w1b, w2b, w3b);
        CFENCE();
        bin[PIDX8(q2)] = o0; bin[PIDX8(q2 + 4)] = o1;
        bin[PIDX8(q2 + 8)] = o2; bin[PIDX8(q2 + 12)] = o3;
        WSYNC();
        // ---- inv stage 3
        z0 = bin[PIDX8(lane)]; z1 = bin[PIDX8(lane + 64)];
        z2 = bin[PIDX8(lane + 128)]; z3 = bin[PIDX8(lane + 192)];
        bfly4<-1>(z0, z1, z2, z3, o0, o1, o2, o3, w1c, w2c, w3c);
        CFENCE();
        bin[PIDX8(q3)] = o0; bin[PIDX8(q3 + 16)] = o1;
        bin[PIDX8(q3 + 32)] = o2; bin[PIDX8(q3 + 48)] = o3;
        WSYNC();
        // ---- inv stage 4 -> time samples stay in registers
        z0 = bin[PIDX8(lane)]; z1 = bin[PIDX8(lane + 64)];
        z2 = bin[PIDX8(lane + 128)]; z3 = bin[PIDX8(lane + 192)];
        bfly4nt<-1>(z0, z1, z2, z3, o0, o1, o2, o3);
        // o0: samples {2l,2l+1}; o1: {2l+128,2l+129}; o2: +256; o3: +384
        // ---- publish windowed second half for the next frame's OLA
        {
            float2 sh0 = make_float2(o2.x * h4, o2.y * h5);
            float2 sh1 = make_float2(o3.x * h6, o3.y * h7);
            float* wrow = (g == NW - 1) ? tails[(it + 1) & 1] : olab[g + 1];
            *reinterpret_cast<float2*>(&wrow[2 * lane])       = sh0;
            *reinterpret_cast<float2*>(&wrow[2 * lane + 128]) = sh1;
        }
        __syncthreads();   // B3: neighbor halves visible
        // ---- OLA + tanh + store
        {
            const float* prow = (g == 0) ? tails[it & 1] : olab[g];
            float2 p0 = *reinterpret_cast<const float2*>(&prow[2 * lane]);
            float2 p1 = *reinterpret_cast<const float2*>(&prow[2 * lane + 128]);
            float2 r0 = make_float2(ftanh((o0.x * h0 + p0.x) * gv),
                                    ftanh((o0.y * h1 + p0.y) * gv));
            float2 r1 = make_float2(ftanh((o1.x * h2 + p1.x) * gv),
                                    ftanh((o1.y * h3 + p1.y) * gv));
            float* dp = dst + (size_t)f * STEP_;
            *reinterpret_cast<float2*>(&dp[2 * lane])       = r0;
            *reinterpret_cast<float2*>(&dp[2 * lane + 128]) = r1;
        }
        // no trailing barrier: buf is wave-private; olab/spec reuse is ordered
        // by next iteration's B1/B2.
    }
}

extern "C" void kernel_launch(void* const* d_in, const int* in_sizes, int n_in,
                              void* d_out, int out_size, void* d_ws, size_t ws_size,
                              hipStream_t stream) {
    (void)in_sizes; (void)n_in; (void)out_size; (void)ws_size;
    const float* x        = (const float*)d_in[0];
    const float* mixer    = (const float*)d_in[1];
    const float* transfer = (const float*)d_in[2];
    const float* gain     = (const float*)d_in[3];
    float* out   = (float*)d_out;
    float* mixed = (float*)d_ws;   // (B, C, T_PAD) f32 = 67.4 MB

    dim3 gmix(T_PAD / 128, 4);
    mix_kernel<<<gmix, 512, 0, stream>>>(x, mixer, mixed);
    stft_kernel<<<256, 1024, 0, stream>>>(mixed, transfer, gain, out);
}

// Round 4
// 113.511 us; speedup vs baseline: 1.7125x; 1.0948x over previous
//
#include <hip/hip_runtime.h>
#include <math.h>

#define T_LEN  65536
#define T_PAD  65792      // T + STEP
#define C_CH   64
#define STEP_  256
#define K_     257        // WS/2 + 1
#define NW     16         // waves per block
#define NIT    16         // iterations (NW frames each)
#define SPEC_ROWF 514     // floats per spec row

// XOR-swizzle: fold float2-index bits[5:4] into bank bits[3:2].
// Stage reads {lane+64m}: lanes l,l+16 land on distinct bank-pairs.
#define SW(i) ((i) ^ (((i) >> 2) & 12))

#define CFENCE() asm volatile("" ::: "memory")
// barrier that does NOT drain vmcnt: prefetch loads stay in flight
#define BAR() do { asm volatile("s_waitcnt lgkmcnt(0)" ::: "memory"); \
                   __builtin_amdgcn_s_barrier(); \
                   asm volatile("" ::: "memory"); } while (0)

__device__ __forceinline__ float2 cadd(float2 a, float2 b) { return make_float2(a.x + b.x, a.y + b.y); }
__device__ __forceinline__ float2 csub(float2 a, float2 b) { return make_float2(a.x - b.x, a.y - b.y); }
__device__ __forceinline__ float2 cmul(float2 a, float2 b) {
    return make_float2(a.x * b.x - a.y * b.y, a.x * b.y + a.y * b.x);
}
template <int SGN>
__device__ __forceinline__ float2 cmulsg(float2 w, float2 t) {
    if (SGN > 0) return make_float2(w.x * t.x - w.y * t.y, w.x * t.y + w.y * t.x);
    else         return make_float2(w.x * t.x + w.y * t.y, w.x * t.y - w.y * t.x);
}
template <int SGN>
__device__ __forceinline__ void bfly4(float2 z0, float2 z1, float2 z2, float2 z3,
                                      float2& o0, float2& o1, float2& o2, float2& o3,
                                      float2 w1, float2 w2, float2 w3) {
    float2 apc = cadd(z0, z2), amc = csub(z0, z2);
    float2 bpd = cadd(z1, z3), bmd = csub(z1, z3);
    float2 jb  = make_float2(-bmd.y, bmd.x);
    float2 t1, t3;
    if (SGN > 0) { t1 = csub(amc, jb); t3 = cadd(amc, jb); }
    else         { t1 = cadd(amc, jb); t3 = csub(amc, jb); }
    o0 = cadd(apc, bpd);
    o1 = cmulsg<SGN>(w1, t1);
    o2 = cmulsg<SGN>(w2, csub(apc, bpd));
    o3 = cmulsg<SGN>(w3, t3);
}
template <int SGN>
__device__ __forceinline__ void bfly4nt(float2 z0, float2 z1, float2 z2, float2 z3,
                                        float2& o0, float2& o1, float2& o2, float2& o3) {
    float2 apc = cadd(z0, z2), amc = csub(z0, z2);
    float2 bpd = cadd(z1, z3), bmd = csub(z1, z3);
    float2 jb  = make_float2(-bmd.y, bmd.x);
    o0 = cadd(apc, bpd);
    o2 = csub(apc, bpd);
    if (SGN > 0) { o1 = csub(amc, jb); o3 = cadd(amc, jb); }
    else         { o1 = cadd(amc, jb); o3 = csub(amc, jb); }
}

__device__ __forceinline__ float ftanh(float x) {
    float e = __expf(2.0f * x);
    return 1.0f - 2.0f * __builtin_amdgcn_rcpf(e + 1.0f);
}

// ---------------- kernel 1: channel mix + zero pad -------------------------
// 2 t-samples per thread, float2 accumulators -> v_pk_fma_f32
__global__ __launch_bounds__(512, 1) void mix_kernel(const float* __restrict__ x,
                                                     const float* __restrict__ mixer,
                                                     float* __restrict__ mixed) {
    __shared__ __align__(16) float xt[64][128];
    __shared__ __align__(16) float mx[64][64];
    int tid = threadIdx.x;
    int b   = blockIdx.y;
    int t0  = blockIdx.x * 128;

    if (t0 >= T_LEN) {   // zero-pad region [T, T_PAD)
        for (int f = tid; f < 8192; f += 512) {
            int d = f >> 7, tt = f & 127;
            mixed[((size_t)(b * C_CH + d)) * T_PAD + t0 + tt] = 0.0f;
        }
        return;
    }
    for (int f = tid; f < 4096; f += 512) reinterpret_cast<float*>(mx)[f] = mixer[f];
    for (int f4 = tid; f4 < 2048; f4 += 512) {
        int cc = f4 >> 5, tt4 = f4 & 31;
        *reinterpret_cast<float4*>(&xt[cc][tt4 * 4]) =
            *reinterpret_cast<const float4*>(&x[((size_t)(b * C_CH + cc)) * T_LEN + t0 + tt4 * 4]);
    }
    __syncthreads();

    int tp = tid & 63, grp = tid >> 6;
    int dbase = grp * 8;
    float2 acc[8];
#pragma unroll
    for (int i = 0; i < 8; ++i) acc[i] = make_float2(0.0f, 0.0f);
    for (int cc = 0; cc < 64; ++cc) {
        float2 xv = *reinterpret_cast<const float2*>(&xt[cc][2 * tp]);
        float4 m0 = *reinterpret_cast<const float4*>(&mx[cc][dbase + 0]);
        float4 m1 = *reinterpret_cast<const float4*>(&mx[cc][dbase + 4]);
        acc[0].x = fmaf(xv.x, m0.x, acc[0].x); acc[0].y = fmaf(xv.y, m0.x, acc[0].y);
        acc[1].x = fmaf(xv.x, m0.y, acc[1].x); acc[1].y = fmaf(xv.y, m0.y, acc[1].y);
        acc[2].x = fmaf(xv.x, m0.z, acc[2].x); acc[2].y = fmaf(xv.y, m0.z, acc[2].y);
        acc[3].x = fmaf(xv.x, m0.w, acc[3].x); acc[3].y = fmaf(xv.y, m0.w, acc[3].y);
        acc[4].x = fmaf(xv.x, m1.x, acc[4].x); acc[4].y = fmaf(xv.y, m1.x, acc[4].y);
        acc[5].x = fmaf(xv.x, m1.y, acc[5].x); acc[5].y = fmaf(xv.y, m1.y, acc[5].y);
        acc[6].x = fmaf(xv.x, m1.z, acc[6].x); acc[6].y = fmaf(xv.y, m1.z, acc[6].y);
        acc[7].x = fmaf(xv.x, m1.w, acc[7].x); acc[7].y = fmaf(xv.y, m1.w, acc[7].y);
    }
#pragma unroll
    for (int i = 0; i < 8; ++i)
        *reinterpret_cast<float2*>(&mixed[((size_t)(b * C_CH + dbase + i)) * T_PAD + t0 + 2 * tp]) = acc[i];
}

// -------- kernel 2: fused STFT -> scan -> iSTFT -> window -> OLA -> tanh ---
// Pipelined: iter it does fwd(it) -> B1 -> [scan(it) || inverse+OLA(it-1)] -> B2.
__global__ __launch_bounds__(1024) void stft_kernel(const float* __restrict__ mixed,
                                                    const float* __restrict__ transfer,
                                                    const float* __restrict__ gainp,
                                                    float* __restrict__ out) {
    __shared__ __align__(16) float2 buf[NW][256];          // swizzled FFT scratch
    __shared__ __align__(16) float2 spec[2][NW][257];      // ping-pong spectra
    __shared__ __align__(16) float  olab[NW][264];         // OLA neighbor exchange
    __shared__ __align__(16) float  tails[2][264];         // iter-crossing tail

    const int tid  = threadIdx.x;
    const int bc   = blockIdx.x;
    const int b    = bc >> 6, c = bc & 63;
    const int g    = tid >> 6, lane = tid & 63;

    const float* src = mixed + ((size_t)(b * C_CH + c)) * T_PAD;
    float*       dst = out   + ((size_t)(b * C_CH + c)) * T_LEN;

    // ---- prefetch iteration 0's frame (z[lane+64m] register layout)
    float2 pf0, pf1, pf2, pf3;
    {
        const float* fp = src + (size_t)g * STEP_;
        pf0 = *reinterpret_cast<const float2*>(fp + 2 * lane);
        pf1 = *reinterpret_cast<const float2*>(fp + 2 * (lane + 64));
        pf2 = *reinterpret_cast<const float2*>(fp + 2 * (lane + 128));
        pf3 = *reinterpret_cast<const float2*>(fp + 2 * (lane + 192));
    }

    // ---- per-lane constant twiddles (registers)
    const float TWO_PI = 6.2831853071795864f;
    float sn, cn;
    sincosf(TWO_PI * (float)lane / 256.0f, &sn, &cn);
    float2 w1a = make_float2(cn, -sn), w2a = cmul(w1a, w1a), w3a = cmul(w2a, w1a);
    sincosf(TWO_PI * (float)(lane >> 2) / 64.0f, &sn, &cn);
    float2 w1b = make_float2(cn, -sn), w2b = cmul(w1b, w1b), w3b = cmul(w2b, w1b);
    sincosf(TWO_PI * (float)(lane >> 4) / 16.0f, &sn, &cn);
    float2 w1c = make_float2(cn, -sn), w2c = cmul(w1c, w1c), w3c = cmul(w2c, w1c);
    float2 wh[4];
#pragma unroll
    for (int qq = 0; qq < 4; ++qq) {
        sincosf(3.14159265358979f * (float)(lane + 64 * qq) / 256.0f, &sn, &cn);
        wh[qq] = make_float2(cn, -sn);
    }
#define HV(m) ((0.5f - 0.5f * cosf(TWO_PI * (float)(m) / 512.0f)) * (1.0f / 512.0f))
    float h0 = HV(2 * lane),       h1 = HV(2 * lane + 1);
    float h2 = HV(2 * lane + 128), h3 = HV(2 * lane + 129);
    float h4 = HV(2 * lane + 256), h5 = HV(2 * lane + 257);
    float h6 = HV(2 * lane + 384), h7 = HV(2 * lane + 385);
#undef HV

    // ---- scan assignment: waves 0-7 all 64 lanes; wave 8 lanes 0,1 take 512/513
    int se = -1;
    if (g < 8) se = (g << 6) | lane;
    else if (g == 8 && lane < 2) se = 512 + lane;
    float tcar = 0.0f, ycar = 0.0f;
    if (se >= 0) tcar = transfer[c * K_ + (se >> 1)];

    if (tid < 256) tails[0][tid] = 0.0f;
    const float gv = gainp[0];
    float2* bin = &buf[g][0];
    const int q2  = (lane & 3)  + ((lane >> 2) << 4);
    const int q3  = (lane & 15) + ((lane >> 4) << 6);
    const int s1b = (4 * lane) ^ (lane & 12);   // SW(4*lane), run of 4 stays contiguous
    BAR();

    for (int it = 0; it <= NIT; ++it) {
        const int sp = it & 1, sp2 = sp ^ 1;
        // ================= forward phase: frame it*NW+g =================
        if (it < NIT) {
            const int f = it * NW + g;
            float2 z0 = pf0, z1 = pf1, z2 = pf2, z3 = pf3;
            if (it + 1 < NIT) {
                const float* fp = src + (size_t)(f + NW) * STEP_;
                pf0 = *reinterpret_cast<const float2*>(fp + 2 * lane);
                pf1 = *reinterpret_cast<const float2*>(fp + 2 * (lane + 64));
                pf2 = *reinterpret_cast<const float2*>(fp + 2 * (lane + 128));
                pf3 = *reinterpret_cast<const float2*>(fp + 2 * (lane + 192));
            }
            float2 o0, o1, o2, o3;
            bfly4<1>(z0, z1, z2, z3, o0, o1, o2, o3, w1a, w2a, w3a);
            {
                float2* bw = bin + s1b;
                *reinterpret_cast<float4*>(bw)     = make_float4(o0.x, o0.y, o1.x, o1.y);
                *reinterpret_cast<float4*>(bw + 2) = make_float4(o2.x, o2.y, o3.x, o3.y);
            }
            CFENCE();
            z0 = bin[SW(lane)]; z1 = bin[SW(lane + 64)];
            z2 = bin[SW(lane + 128)]; z3 = bin[SW(lane + 192)];
            bfly4<1>(z0, z1, z2, z3, o0, o1, o2, o3, w1b, w2b, w3b);
            CFENCE();
            bin[SW(q2)] = o0; bin[SW(q2 + 4)] = o1;
            bin[SW(q2 + 8)] = o2; bin[SW(q2 + 12)] = o3;
            CFENCE();
            z0 = bin[SW(lane)]; z1 = bin[SW(lane + 64)];
            z2 = bin[SW(lane + 128)]; z3 = bin[SW(lane + 192)];
            bfly4<1>(z0, z1, z2, z3, o0, o1, o2, o3, w1c, w2c, w3c);
            CFENCE();
            bin[SW(q3)] = o0; bin[SW(q3 + 16)] = o1;
            bin[SW(q3 + 32)] = o2; bin[SW(q3 + 48)] = o3;
            CFENCE();
            z0 = bin[SW(lane)]; z1 = bin[SW(lane + 64)];
            z2 = bin[SW(lane + 128)]; z3 = bin[SW(lane + 192)];
            bfly4nt<1>(z0, z1, z2, z3, o0, o1, o2, o3);
            CFENCE();
            bin[SW(lane)] = o0; bin[SW(lane + 64)] = o1;
            bin[SW(lane + 128)] = o2; bin[SW(lane + 192)] = o3;
            CFENCE();
            // Hermitian split -> spec[sp][g]
#pragma unroll
            for (int qq = 0; qq < 4; ++qq) {
                int k = lane + 64 * qq;
                float2 u = bin[SW(k)];
                float2 v = bin[SW((256 - k) & 255)];
                float2 E = make_float2(0.5f * (u.x + v.x),  0.5f * (u.y - v.y));
                float2 O = make_float2(0.5f * (u.y + v.y), -0.5f * (u.x - v.x));
                spec[sp][g][k] = cadd(E, cmul(wh[qq], O));
            }
            if (lane == 0) {
                float2 u0 = bin[SW(0)];
                spec[sp][g][256] = make_float2(u0.x - u0.y, 0.0f);
            }
        }
        BAR();   // B1: spec[sp] complete; previous olab consumed
        // ================= scan(it) [waves 0-8] =================
        if (it < NIT && se >= 0) {
            float* sf = reinterpret_cast<float*>(&spec[sp][0][0]);
            float y = ycar;
#pragma unroll
            for (int gg = 0; gg < NW; ++gg) {
                y = (sf[gg * SPEC_ROWF + se] + y) * tcar;
                sf[gg * SPEC_ROWF + se] = y;
            }
            ycar = y;
        }
        // ============ inverse + OLA for frames (it-1)*NW+g ============
        if (it > 0) {
            const int fb = (it - 1) * NW + g;
            float2 o0, o1, o2, o3;
            {
                float2 zz[4];
#pragma unroll
                for (int qq = 0; qq < 4; ++qq) {
                    int k = lane + 64 * qq;
                    float2 u  = spec[sp2][g][k];
                    float2 s2 = spec[sp2][g][256 - k];
                    float2 A  = make_float2(u.x + s2.x, u.y - s2.y);
                    float2 D  = make_float2(u.x - s2.x, u.y + s2.y);
                    float2 Bv = cmulsg<-1>(wh[qq], D);
                    zz[qq] = make_float2(A.x - Bv.y, A.y + Bv.x);
                }
                bfly4<-1>(zz[0], zz[1], zz[2], zz[3], o0, o1, o2, o3, w1a, w2a, w3a);
            }
            {
                float2* bw = bin + s1b;
                *reinterpret_cast<float4*>(bw)     = make_float4(o0.x, o0.y, o1.x, o1.y);
                *reinterpret_cast<float4*>(bw + 2) = make_float4(o2.x, o2.y, o3.x, o3.y);
            }
            CFENCE();
            float2 z0 = bin[SW(lane)], z1 = bin[SW(lane + 64)];
            float2 z2 = bin[SW(lane + 128)], z3 = bin[SW(lane + 192)];
            bfly4<-1>(z0, z1, z2, z3, o0, o1, o2, o3, w1b, w2b, w3b);
            CFENCE();
            bin[SW(q2)] = o0; bin[SW(q2 + 4)] = o1;
            bin[SW(q2 + 8)] = o2; bin[SW(q2 + 12)] = o3;
            CFENCE();
            z0 = bin[SW(lane)]; z1 = bin[SW(lane + 64)];
            z2 = bin[SW(lane + 128)]; z3 = bin[SW(lane + 192)];
            bfly4<-1>(z0, z1, z2, z3, o0, o1, o2, o3, w1c, w2c, w3c);
            CFENCE();
            bin[SW(q3)] = o0; bin[SW(q3 + 16)] = o1;
            bin[SW(q3 + 32)] = o2; bin[SW(q3 + 48)] = o3;
            CFENCE();
            z0 = bin[SW(lane)]; z1 = bin[SW(lane + 64)];
            z2 = bin[SW(lane + 128)]; z3 = bin[SW(lane + 192)];
            bfly4nt<-1>(z0, z1, z2, z3, o0, o1, o2, o3);
            // publish windowed second half for neighbor / next-iter tail
            {
                float2 sh0 = make_float2(o2.x * h4, o2.y * h5);
                float2 sh1 = make_float2(o3.x * h6, o3.y * h7);
                float* wrow = (g == NW - 1) ? tails[it & 1] : olab[g + 1];
                *reinterpret_cast<float2*>(&wrow[2 * lane])       = sh0;
                *reinterpret_cast<float2*>(&wrow[2 * lane + 128]) = sh1;
            }
            BAR();   // B2: neighbor halves visible
            {
                const float* prow = (g == 0) ? tails[(it - 1) & 1] : olab[g];
                float2 p0 = *reinterpret_cast<const float2*>(&prow[2 * lane]);
                float2 p1 = *reinterpret_cast<const float2*>(&prow[2 * lane + 128]);
                float2 r0 = make_float2(ftanh((o0.x * h0 + p0.x) * gv),
                                        ftanh((o0.y * h1 + p0.y) * gv));
                float2 r1 = make_float2(ftanh((o1.x * h2 + p1.x) * gv),
                                        ftanh((o1.y * h3 + p1.y) * gv));
                float* dp = dst + (size_t)fb * STEP_;
                *reinterpret_cast<float2*>(&dp[2 * lane])       = r0;
                *reinterpret_cast<float2*>(&dp[2 * lane + 128]) = r1;
            }
        }
    }
}

extern "C" void kernel_launch(void* const* d_in, const int* in_sizes, int n_in,
                              void* d_out, int out_size, void* d_ws, size_t ws_size,
                              hipStream_t stream) {
    (void)in_sizes; (void)n_in; (void)out_size; (void)ws_size;
    const float* x        = (const float*)d_in[0];
    const float* mixer    = (const float*)d_in[1];
    const float* transfer = (const float*)d_in[2];
    const float* gain     = (const float*)d_in[3];
    float* out   = (float*)d_out;
    float* mixed = (float*)d_ws;   // (B, C, T_PAD) f32 = 67.4 MB

    dim3 gmix(T_PAD / 128, 4);
    mix_kernel<<<gmix, 512, 0, stream>>>(x, mixer, mixed);
    stft_kernel<<<256, 1024, 0, stream>>>(mixed, transfer, gain, out);
}